// Round 2
// baseline (674.301 us; speedup 1.0000x reference)
//
#include <hip/hip_runtime.h>

#define NEG_VAL -1000000000.0f

// clang native vector type — __builtin_nontemporal_store accepts this
// (HIP's float4 is a class and is rejected).
typedef float v4f __attribute__((ext_vector_type(4)));

// Fused kernel:
//   blocks [0, dotBlocks)              : per-node partial dots (one 64-lane wave per node)
//       a[n] = dot(h[n], W[0:128])     (used when n is a dest)
//       c[n] = dot(h[n], W[128:256])   (used when n is a source)
//   blocks [dotBlocks, dotBlocks+fillBlocks) : grid-stride NT fill of the N x N matrix
// The dot blocks read only ~6.3 MB; they hide entirely under the 604 MB write stream.
__global__ __launch_bounds__(256) void dots_and_fill(
    const float* __restrict__ h,
    const float* __restrict__ W,
    float* __restrict__ a,
    float* __restrict__ c,
    int N,
    v4f* __restrict__ out4,
    long long n4,
    int dotBlocks,
    int fillBlocks)
{
    if ((int)blockIdx.x < dotBlocks) {
        int gid  = blockIdx.x * 256 + threadIdx.x;
        int node = gid >> 6;
        int lane = threadIdx.x & 63;
        if (node >= N) return;

        const float2* h2 = (const float2*)(h + (size_t)node * 128);
        float2 v  = h2[lane];
        float2 wd = ((const float2*)W)[lane];           // W[2*lane], W[2*lane+1]
        float2 ws = ((const float2*)(W + 128))[lane];   // W[128+2*lane], ...

        float sd = v.x * wd.x + v.y * wd.y;
        float ss = v.x * ws.x + v.y * ws.y;

        #pragma unroll
        for (int off = 32; off; off >>= 1) {
            sd += __shfl_xor(sd, off, 64);
            ss += __shfl_xor(ss, off, 64);
        }
        if (lane == 0) {
            a[node] = sd;
            c[node] = ss;
        }
    } else {
        // Write-once data: nontemporal float4 stores, grid-stride so each
        // thread issues ~36 independent 16B stores (deep store queue, few WGs).
        long long tid    = (long long)(blockIdx.x - dotBlocks) * 256 + threadIdx.x;
        long long stride = (long long)fillBlocks * 256;
        const v4f v = { NEG_VAL, NEG_VAL, NEG_VAL, NEG_VAL };
        for (long long i = tid; i < n4; i += stride) {
            __builtin_nontemporal_store(v, out4 + i);
        }
    }
}

// Per-edge scatter of the linear-layer output.
// val = a[d] + c[s] + wgt*W[256] + b ; out[d*N + s] = val
__global__ __launch_bounds__(256) void edge_scatter(
    const int* __restrict__ src,
    const int* __restrict__ dst,
    const float* __restrict__ wgt,
    const float* __restrict__ a,
    const float* __restrict__ c,
    const float* __restrict__ W,
    const float* __restrict__ b,
    float* __restrict__ out,
    int E, int N)
{
    int e = blockIdx.x * blockDim.x + threadIdx.x;
    if (e >= E) return;
    int s = src[e];
    int d = dst[e];
    float val = fmaf(wgt[e], W[256], a[d] + c[s] + b[0]);
    out[(size_t)d * N + s] = val;
}

extern "C" void kernel_launch(void* const* d_in, const int* in_sizes, int n_in,
                              void* d_out, int out_size, void* d_ws, size_t ws_size,
                              hipStream_t stream) {
    const float* h       = (const float*)d_in[0];  // [N, 128]
    const int*   sources = (const int*)d_in[1];    // [E]
    const int*   dests   = (const int*)d_in[2];    // [E]
    const float* weights = (const float*)d_in[3];  // [E]
    const float* W       = (const float*)d_in[4];  // [257]
    const float* b       = (const float*)d_in[5];  // [1]
    float* out = (float*)d_out;                    // [N, N]

    const int N = in_sizes[0] / 128;               // 12288
    const int E = in_sizes[1];                     // 393216

    float* a = (float*)d_ws;                       // [N]
    float* c = a + N;                              // [N]

    // 1) fused: node dots + NEG fill
    {
        int dotBlocks  = (N + 3) / 4;              // 4 waves (nodes) per 256-thread block
        int fillBlocks = 4096;                     // grid-stride over 37.7M float4s
        long long n4 = (long long)out_size / 4;    // out_size is N*N elements
        dots_and_fill<<<dotBlocks + fillBlocks, 256, 0, stream>>>(
            h, W, a, c, N, (v4f*)out, n4, dotBlocks, fillBlocks);
    }

    // 2) scatter edge values (depends on fill + dots; same stream serializes)
    {
        int blocks = (E + 255) / 256;
        edge_scatter<<<blocks, 256, 0, stream>>>(sources, dests, weights, a, c, W, b,
                                                 out, E, N);
    }
}

// Round 3
// 630.342 us; speedup vs baseline: 1.0697x; 1.0697x over previous
//
#include <hip/hip_runtime.h>

#define NEG_VAL -1000000000.0f

// Fused kernel, fill-first ordering:
//   blocks [0, fillBlocks)                 : NEG fill, ONE plain float4 store per
//                                            thread (the pattern that ran at ~6 TB/s
//                                            in the 629.9us baseline; NT stores and
//                                            grid-stride both regressed in R2).
//   blocks [fillBlocks, fillBlocks+dotBlocks): per-node partial dots, one 64-lane
//                                            wave per node. Dispatched LAST so the
//                                            write stream starts immediately; their
//                                            6.3 MB of reads hide under the writes.
//       a[n] = dot(h[n], W[0:128])   (used when n is a dest)
//       c[n] = dot(h[n], W[128:256]) (used when n is a source)
__global__ __launch_bounds__(256) void fill_and_dots(
    float4* __restrict__ out4,
    long long n4,
    int fillBlocks,
    const float* __restrict__ h,
    const float* __restrict__ W,
    float* __restrict__ a,
    float* __restrict__ c,
    int N)
{
    if ((int)blockIdx.x < fillBlocks) {
        long long i = (long long)blockIdx.x * 256 + threadIdx.x;
        if (i < n4) {
            out4[i] = make_float4(NEG_VAL, NEG_VAL, NEG_VAL, NEG_VAL);
        }
    } else {
        int gid  = (blockIdx.x - fillBlocks) * 256 + threadIdx.x;
        int node = gid >> 6;
        int lane = threadIdx.x & 63;
        if (node >= N) return;

        const float2* h2 = (const float2*)(h + (size_t)node * 128);
        float2 v  = h2[lane];
        float2 wd = ((const float2*)W)[lane];           // W[2*lane], W[2*lane+1]
        float2 ws = ((const float2*)(W + 128))[lane];   // W[128+2*lane], ...

        float sd = v.x * wd.x + v.y * wd.y;
        float ss = v.x * ws.x + v.y * ws.y;

        #pragma unroll
        for (int off = 32; off; off >>= 1) {
            sd += __shfl_xor(sd, off, 64);
            ss += __shfl_xor(ss, off, 64);
        }
        if (lane == 0) {
            a[node] = sd;
            c[node] = ss;
        }
    }
}

// Per-edge scatter of the linear-layer output.
// val = a[d] + c[s] + wgt*W[256] + b ; out[d*N + s] = val
__global__ __launch_bounds__(256) void edge_scatter(
    const int* __restrict__ src,
    const int* __restrict__ dst,
    const float* __restrict__ wgt,
    const float* __restrict__ a,
    const float* __restrict__ c,
    const float* __restrict__ W,
    const float* __restrict__ b,
    float* __restrict__ out,
    int E, int N)
{
    int e = blockIdx.x * blockDim.x + threadIdx.x;
    if (e >= E) return;
    int s = src[e];
    int d = dst[e];
    float val = fmaf(wgt[e], W[256], a[d] + c[s] + b[0]);
    out[(size_t)d * N + s] = val;
}

extern "C" void kernel_launch(void* const* d_in, const int* in_sizes, int n_in,
                              void* d_out, int out_size, void* d_ws, size_t ws_size,
                              hipStream_t stream) {
    const float* h       = (const float*)d_in[0];  // [N, 128]
    const int*   sources = (const int*)d_in[1];    // [E]
    const int*   dests   = (const int*)d_in[2];    // [E]
    const float* weights = (const float*)d_in[3];  // [E]
    const float* W       = (const float*)d_in[4];  // [257]
    const float* b       = (const float*)d_in[5];  // [1]
    float* out = (float*)d_out;                    // [N, N]

    const int N = in_sizes[0] / 128;               // 12288
    const int E = in_sizes[1];                     // 393216

    float* a = (float*)d_ws;                       // [N]
    float* c = a + N;                              // [N]

    // 1) fused: NEG fill (first) + node dots (trailing blocks)
    {
        long long n4 = (long long)out_size / 4;            // out_size = N*N elements
        int fillBlocks = (int)((n4 + 255) / 256);          // one float4 per thread
        int dotBlocks  = (N + 3) / 4;                      // 4 waves (nodes) per block
        fill_and_dots<<<fillBlocks + dotBlocks, 256, 0, stream>>>(
            (float4*)out, n4, fillBlocks, h, W, a, c, N);
    }

    // 2) scatter edge values (depends on fill + dots; same stream serializes)
    {
        int blocks = (E + 255) / 256;
        edge_scatter<<<blocks, 256, 0, stream>>>(sources, dests, weights, a, c, W, b,
                                                 out, E, N);
    }
}